// Round 15
// baseline (418.406 us; speedup 1.0000x reference)
//
#include <hip/hip_runtime.h>

#define S_LEN 2048
#define QKV_N 4096
// SCALE_Q * log2(e): logits land in log2 domain, softmax uses v_exp_f32 (exp2)
#define SCALE_Q_LOG2E 0.12751744461f

typedef __attribute__((ext_vector_type(8))) short short8;
typedef __attribute__((ext_vector_type(4))) float f32x4;
typedef __attribute__((ext_vector_type(16))) float f32x16;
typedef __attribute__((ext_vector_type(4))) float floatv4;
typedef __attribute__((ext_vector_type(4))) unsigned short ushortv4;
typedef __attribute__((ext_vector_type(2))) unsigned int uint2v;

__device__ __forceinline__ float bf2f(unsigned short u) {
  union { unsigned u; float f; } x; x.u = ((unsigned)u) << 16; return x.f;
}
__device__ __forceinline__ unsigned short f2bf(float f) {
  union { float f; unsigned u; } x; x.f = f;
  unsigned r = x.u + 0x7fffu + ((x.u >> 16) & 1u);
  return (unsigned short)(r >> 16);
}

typedef const unsigned int __attribute__((address_space(1)))* gas1_t;
typedef unsigned int __attribute__((address_space(3)))* las3_t;
#define GLL16(g, l) __builtin_amdgcn_global_load_lds((gas1_t)(const void*)(g), (las3_t)(void*)(l), 16, 0, 0)

// fast exp2: raw v_exp_f32, no libm fixup path
#define EXP2F(x) __builtin_amdgcn_exp2f(x)

// ---------------- f32 -> bf16 convert (vectorized) ----------------
__global__ __launch_bounds__(256) void k_cvt(const float* __restrict__ in,
                                             unsigned short* __restrict__ out, int n4) {
  int i = blockIdx.x * 256 + threadIdx.x;
  if (i >= n4) return;
  floatv4 v = ((const floatv4*)in)[i];
  ushortv4 o;
  o[0] = f2bf(v[0]); o[1] = f2bf(v[1]); o[2] = f2bf(v[2]); o[3] = f2bf(v[3]);
  ((ushortv4*)out)[i] = o;
}

// ---------------- transpose + convert: in[R][C] f32 -> out[C][R] bf16 ----------------
__global__ __launch_bounds__(256) void k_transpose_cvt(const float* __restrict__ in,
                                                       unsigned short* __restrict__ out,
                                                       int R, int C) {
  __shared__ float t[64][65];
  int bx = blockIdx.x;
  int by = blockIdx.y;
#pragma unroll
  for (int i = 0; i < 16; ++i) {
    int idx = threadIdx.x + i * 256;
    int r = idx >> 6, c = idx & 63;
    t[r][c] = in[(size_t)(by * 64 + r) * C + bx * 64 + c];
  }
  __syncthreads();
#pragma unroll
  for (int i = 0; i < 16; ++i) {
    int idx = threadIdx.x + i * 256;
    int r = idx >> 6, c = idx & 63;
    out[(size_t)(bx * 64 + r) * R + by * 64 + c] = f2bf(t[c][r]);
  }
}

// ---------------- 256x256x(BK=64) bf16 GEMM, 8 waves, 4-phase pipelined ----------------
// R12 known-best: 16x16x32 MFMA, phases = (k-slice, m-half), 24 conflict-free
// reads/tile, spread staging, vmcnt(0)+barrier at p==3 only.
template <int OUT_BF16>
__global__ __launch_bounds__(512, 2) void k_gemm256(const unsigned short* __restrict__ A,
                                                    const unsigned short* __restrict__ BT,
                                                    void* __restrict__ Cout,
                                                    int M, int N, int K) {
  const int tid = threadIdx.x;
  const int lane = tid & 63;
  const int wid = tid >> 6;
  const int wr = wid >> 2;          // 0..1 over M (128 rows each)
  const int wc = wid & 3;           // 0..3 over N (64 cols each)
  const int lr = lane & 15, lg = lane >> 4;

  // T1: bijective XCD-aware block swizzle (nwg % 8 == 0)
  const int gx = gridDim.x;
  const int nwg = gx * gridDim.y;
  const int lid = blockIdx.y * gx + blockIdx.x;
  const int qc = nwg >> 3;
  const int swz = (lid & 7) * qc + (lid >> 3);
  const int row0 = (swz / gx) * 256, col0 = (swz % gx) * 256;

  __shared__ __align__(16) unsigned short As[2][256 * 64];
  __shared__ __align__(16) unsigned short Bs[2][256 * 64];

  f32x4 acc[8][4];
#pragma unroll
  for (int m = 0; m < 8; ++m)
#pragma unroll
    for (int n = 0; n < 4; ++n) acc[m][n] = (f32x4){0.f, 0.f, 0.f, 0.f};

  const int r1 = tid >> 3, c1 = tid & 7;
  const int r2 = (tid + 512) >> 3, c2 = (tid + 512) & 7;
  const size_t so1 = (size_t)r1 * K + (size_t)((c1 ^ (r1 & 7)) * 8);
  const size_t so2 = (size_t)r2 * K + (size_t)((c2 ^ (r2 & 7)) * 8);
  const unsigned ld1 = (unsigned)tid * 16, ld2 = (unsigned)(tid + 512) * 16;

  const unsigned short* Abase = A + (size_t)row0 * K;
  const unsigned short* Bbase = BT + (size_t)col0 * K;

  auto stage = [&](int ph, int kt, int buf) {
    const size_t hb = (size_t)(ph >> 1) * 128 * K + (size_t)kt * 64;
    const unsigned short* src;
    unsigned short* dst;
    if (ph & 1) { src = Bbase + hb; dst = &Bs[buf][(ph >> 1) * 128 * 64]; }
    else        { src = Abase + hb; dst = &As[buf][(ph >> 1) * 128 * 64]; }
    GLL16(src + so1, (char*)dst + ld1);
    GLL16(src + so2, (char*)dst + ld2);
  };

#pragma unroll
  for (int ph = 0; ph < 4; ++ph) stage(ph, 0, 0);
  asm volatile("s_waitcnt vmcnt(0)" ::: "memory");
  __builtin_amdgcn_s_barrier();

  const int NT = K >> 6;
  for (int t = 0; t < NT; ++t) {
    const int cur = t & 1;
    const char* Ab = (const char*)&As[cur][0];
    const char* Bb = (const char*)&Bs[cur][0];
    short8 bf[4];
#pragma unroll
    for (int p = 0; p < 4; ++p) {
      const int ks = p >> 1, half = p & 1;
      short8 af[4];
#pragma unroll
      for (int m = 0; m < 4; ++m) {
        int rA = wr * 128 + (half * 4 + m) * 16 + lr;
        af[m] = *(const short8*)(Ab +
                ((rA * 128 + (ks * 4 + lg) * 16) ^ ((rA & 7) << 4)));
      }
      if (half == 0) {
#pragma unroll
        for (int n = 0; n < 4; ++n) {
          int rB = wc * 64 + n * 16 + lr;
          bf[n] = *(const short8*)(Bb +
                  ((rB * 128 + (ks * 4 + lg) * 16) ^ ((rB & 7) << 4)));
        }
      }
      if (t + 1 < NT) stage(p, t + 1, cur ^ 1);
      __builtin_amdgcn_sched_barrier(0);
      __builtin_amdgcn_s_setprio(1);
#pragma unroll
      for (int m = 0; m < 4; ++m)
#pragma unroll
        for (int n = 0; n < 4; ++n)
          acc[half * 4 + m][n] = __builtin_amdgcn_mfma_f32_16x16x32_bf16(
              af[m], bf[n], acc[half * 4 + m][n], 0, 0, 0);
      __builtin_amdgcn_s_setprio(0);
      if (p == 3) asm volatile("s_waitcnt vmcnt(0)" ::: "memory");
      __builtin_amdgcn_s_barrier();
    }
  }

  if (OUT_BF16) {
    unsigned short* C = (unsigned short*)Cout;
#pragma unroll
    for (int m = 0; m < 8; ++m)
#pragma unroll
      for (int n = 0; n < 4; ++n)
#pragma unroll
        for (int r = 0; r < 4; ++r)
          C[(size_t)(row0 + wr * 128 + m * 16 + 4 * lg + r) * N + col0 + wc * 64 + n * 16 + lr] =
              f2bf(acc[m][n][r]);
  } else {
    float* C = (float*)Cout;
#pragma unroll
    for (int m = 0; m < 8; ++m)
#pragma unroll
      for (int n = 0; n < 4; ++n)
#pragma unroll
        for (int r = 0; r < 4; ++r)
          C[(size_t)(row0 + wr * 128 + m * 16 + 4 * lg + r) * N + col0 + wc * 64 + n * 16 + lr] =
              acc[m][n][r];
  }
}

// ---------------- per-head RMSNorm + RoPE (in-place on bf16 qkv) ----------------
// R15: vectorized -- lane loads ONE u32 (elems 2l,2l+1 of the 128-elem head
// row), RoPE partner values (elems 2l±64, in lane l^32) via shfl_xor(32);
// sign=-1 for x1-half, +1 for x2-half. 1x4B load + 1x4B store per lane
// (was 2x2B scalar loads + 2x2B scalar stores -- Common-mistake #2).
__global__ __launch_bounds__(256) void k_normrope(unsigned short* __restrict__ qkv,
                                                  const int* __restrict__ pos,
                                                  const float* __restrict__ qw,
                                                  const float* __restrict__ kw) {
  int lane = threadIdx.x & 63;
  int wv = (blockIdx.x << 2) + (threadIdx.x >> 6);
  int bs = wv / 24, hr = wv - bs * 24;
  bool isq = hr < 16;
  int col0 = isq ? hr * 128 : 2048 + (hr - 16) * 128;
  unsigned short* row = qkv + (size_t)bs * QKV_N + col0;

  unsigned v = *(const unsigned*)(row + 2 * lane);
  float a = bf2f((unsigned short)(v & 0xffff));
  float b = bf2f((unsigned short)(v >> 16));

  float ss = a * a + b * b;
#pragma unroll
  for (int m = 1; m < 64; m <<= 1) ss += __shfl_xor(ss, m, 64);
  float rn = rsqrtf(ss * (1.0f / 128.0f) + 1e-6f);

  const float* w = isq ? qw : kw;
  float an = a * rn * w[2 * lane];
  float bn = b * rn * w[2 * lane + 1];

  // RoPE partners (elems 2l^64, 2l^64+1) live in lane l^32
  float pa = __shfl_xor(an, 32, 64);
  float pb = __shfl_xor(bn, 32, 64);

  float p = (float)pos[bs];
  int f0 = (2 * lane) & 63, f1 = (2 * lane + 1) & 63;
  float ang0 = p * exp2f(-(float)f0 * 0.20762050593045951f);
  float ang1 = p * exp2f(-(float)f1 * 0.20762050593045951f);
  float sgn = (lane < 32) ? -1.0f : 1.0f;   // x1: cos*x1 - sin*x2 ; x2: cos*x2 + sin*x1
  float o0 = an * __cosf(ang0) + sgn * pa * __sinf(ang0);
  float o1 = bn * __cosf(ang1) + sgn * pb * __sinf(ang1);

  // Q absorbs SCALE * log2(e) so attn softmax runs in exp2 domain
  float sc = isq ? SCALE_Q_LOG2E : 1.0f;
  unsigned outv = (unsigned)f2bf(o0 * sc) | ((unsigned)f2bf(o1 * sc) << 16);
  *(unsigned*)(row + 2 * lane) = outv;
}

// ---------------- flash attention, 8-warp swapped-QK^T structure ----------------
// grid (S/256, B*NH); 8 waves x 32 q-rows. KVBLK=64, 32x32x16 MFMA.
// R10-best exact: XCD remap + PV tr-read pipeline, permlane repack,
// log2-domain softmax via raw v_exp_f32, serial max/sum chains.
__global__ __launch_bounds__(512, 2) void k_attn(const unsigned short* __restrict__ qkv,
                                                 unsigned short* __restrict__ ctx) {
  const int tid = threadIdx.x;
  const int lane = tid & 63;
  const int wid = tid >> 6;
  const int hi = lane >> 5;
  const int l15 = lane & 15;
  const int q31 = lane & 31;
  // XCD remap: give each XCD 8 consecutive bh (= 4 (b,kvh) K/V sets = 2MB, L2-fits)
  const int lid0 = blockIdx.y * 8 + blockIdx.x;
  const int xcd = lid0 & 7, idx = lid0 >> 3;
  const int bh = xcd * 8 + (idx & 7);
  const int qb = idx >> 3;
  const int b = bh >> 4, h = bh & 15, kvh = h >> 1;

  __shared__ __align__(16) unsigned short Ks[2][64 * 128];
  __shared__ __align__(16) unsigned short Vs[2][64 * 128];

  const size_t baseRow = (size_t)b * S_LEN;
  const int qrow = qb * 256 + wid * 32 + q31;

  const unsigned short* Qg = qkv + (baseRow + qrow) * QKV_N + h * 128;
  short8 qf[8];
#pragma unroll
  for (int c = 0; c < 8; ++c)
    qf[c] = *(const short8*)(Qg + c * 16 + hi * 8);

  const unsigned short* Kg = qkv + baseRow * QKV_N + 2048 + kvh * 128;
  const unsigned short* Vg = Kg + 1024;

  size_t ksrc[2], vsrc[2];
  unsigned sdst[2];
#pragma unroll
  for (int i = 0; i < 2; ++i) {
    int s = tid + i * 512;
    int krow = s >> 4, kc = s & 15;
    ksrc[i] = (size_t)krow * QKV_N + (size_t)((kc ^ (krow & 7)) * 8);
    int st = s >> 3, in8 = s & 7;
    int vkey = (st >> 3) * 4 + (in8 >> 1);
    int vj = ((st & 7) << 1) | (in8 & 1);
    vsrc[i] = (size_t)vkey * QKV_N + (size_t)(vj * 8);
    sdst[i] = (unsigned)s * 16;
  }

#define STAGE(T, BUF)                                                    \
  {                                                                      \
    size_t toff = (size_t)(T) * 64 * QKV_N;                              \
    GLL16(Kg + toff + ksrc[0], (char*)Ks[BUF] + sdst[0]);                \
    GLL16(Kg + toff + ksrc[1], (char*)Ks[BUF] + sdst[1]);                \
    GLL16(Vg + toff + vsrc[0], (char*)Vs[BUF] + sdst[0]);                \
    GLL16(Vg + toff + vsrc[1], (char*)Vs[BUF] + sdst[1]);                \
  }

  f32x16 acc[4];
#pragma unroll
  for (int d = 0; d < 4; ++d)
#pragma unroll
    for (int r = 0; r < 16; ++r) acc[d][r] = 0.f;
  float m_run = -1e30f, l_run = 0.f;

  const unsigned vbase = (unsigned)(uintptr_t)&Vs[0][0];
  const int sw = (q31 & 7) << 4;

  // issue 8 tr-reads for one ks-group into vr[8]
  auto tr_issue = [&](uint2v* vr, int ksg, unsigned vb) {
#pragma unroll
    for (int db = 0; db < 4; ++db)
#pragma unroll
      for (int rd = 0; rd < 2; ++rd) {
        int st = (ksg * 4 + hi * 2 + rd) * 8 + db * 2 + ((lane >> 4) & 1);
        unsigned a = vb + (unsigned)(st * 128 + l15 * 8);
        asm volatile("ds_read_b64_tr_b16 %0, %1" : "=v"(vr[db * 2 + rd]) : "v"(a));
      }
  };

  STAGE(0, 0);

  for (int t = 0; t < 32; ++t) {
    const int cur = t & 1;
    __builtin_amdgcn_s_barrier();          // all waves done reading buf[cur^1]
    __builtin_amdgcn_sched_barrier(0);
    if (t < 31) {
      STAGE(t + 1, cur ^ 1);
      asm volatile("s_waitcnt vmcnt(4)" ::: "memory");
    } else {
      asm volatile("s_waitcnt vmcnt(0)" ::: "memory");
    }
    __builtin_amdgcn_s_barrier();          // buf[cur] ready
    __builtin_amdgcn_sched_barrier(0);

    // ---- QK^T (swapped): p[key][q], lane owns q-row = lane&31 ----
    const char* Kb = (const char*)Ks[cur];
    f32x16 p0, p1;
#pragma unroll
    for (int r = 0; r < 16; ++r) { p0[r] = 0.f; p1[r] = 0.f; }
#pragma unroll
    for (int c = 0; c < 8; ++c) {
      int cb = c * 32 + hi * 16;
      short8 k0 = *(const short8*)(Kb + q31 * 256 + (cb ^ sw));
      short8 k1 = *(const short8*)(Kb + (32 + q31) * 256 + (cb ^ sw));
      p0 = __builtin_amdgcn_mfma_f32_32x32x16_bf16(k0, qf[c], p0, 0, 0, 0);
      p1 = __builtin_amdgcn_mfma_f32_32x32x16_bf16(k1, qf[c], p1, 0, 0, 0);
    }

    // ---- online softmax (log2 domain, raw v_exp_f32), in-lane ----
    float mt = p0[0];
#pragma unroll
    for (int r = 1; r < 16; ++r) mt = fmaxf(mt, p0[r]);
#pragma unroll
    for (int r = 0; r < 16; ++r) mt = fmaxf(mt, p1[r]);
    mt = fmaxf(mt, __shfl_xor(mt, 32, 64));
    if (!__all(mt - m_run <= 8.0f)) {     // defer-max: P bounded by 2^8
      float mnew = fmaxf(m_run, mt);
      float corr = EXP2F(m_run - mnew);
      l_run *= corr;
#pragma unroll
      for (int d = 0; d < 4; ++d)
#pragma unroll
        for (int r = 0; r < 16; ++r) acc[d][r] *= corr;
      m_run = mnew;
    }
    float s_loc = 0.f;
#pragma unroll
    for (int r = 0; r < 16; ++r) { p0[r] = EXP2F(p0[r] - m_run); s_loc += p0[r]; }
#pragma unroll
    for (int r = 0; r < 16; ++r) { p1[r] = EXP2F(p1[r] - m_run); s_loc += p1[r]; }
    l_run += s_loc + __shfl_xor(s_loc, 32, 64);

    // ---- PV (swapped): acc[d][q] += V^T x P; tr-reads pipelined 1 group ahead ----
    const unsigned vb = vbase + (unsigned)cur * 16384u;
    const float* pp0 = (const float*)&p0;
    const float* pp1 = (const float*)&p1;
    uint2v vrA[8], vrB[8];
    tr_issue(vrA, 0, vb);
#pragma unroll
    for (int ks = 0; ks < 4; ++ks) {
      const float* pr = ((ks & 2) ? pp1 : pp0) + (ks & 1) * 8;
      unsigned t0, t1, u0, u1;
      asm("v_cvt_pk_bf16_f32 %0, %1, %2" : "=v"(t0) : "v"(pr[0]), "v"(pr[1]));
      asm("v_cvt_pk_bf16_f32 %0, %1, %2" : "=v"(t1) : "v"(pr[2]), "v"(pr[3]));
      asm("v_cvt_pk_bf16_f32 %0, %1, %2" : "=v"(u0) : "v"(pr[4]), "v"(pr[5]));
      asm("v_cvt_pk_bf16_f32 %0, %1, %2" : "=v"(u1) : "v"(pr[6]), "v"(pr[7]));
      // cross-half repack in VALU (R3/R4/R9-validated): distinct source values,
      // no CSE-aliasing hazard (t0!=u0, t1!=u1 by construction)
      asm("v_permlane32_swap_b32 %0, %1" : "+v"(t0), "+v"(u0));
      asm("v_permlane32_swap_b32 %0, %1" : "+v"(t1), "+v"(u1));
      union { unsigned u[4]; short8 s; } pa;
      pa.u[0] = t0; pa.u[1] = t1; pa.u[2] = u0; pa.u[3] = u1;

      if (ks == 0) tr_issue(vrB, 1, vb);
      else if (ks == 1) tr_issue(vrA, 2, vb);
      else if (ks == 2) tr_issue(vrB, 3, vb);

      if (ks < 3) asm volatile("s_waitcnt lgkmcnt(8)" ::: "memory");
      else        asm volatile("s_waitcnt lgkmcnt(0)" ::: "memory");
      __builtin_amdgcn_sched_barrier(0);
#pragma unroll
      for (int db = 0; db < 4; ++db) {
        union { uint2v v[2]; short8 s; } vf;
        if (ks & 1) { vf.v[0] = vrB[db * 2]; vf.v[1] = vrB[db * 2 + 1]; }
        else        { vf.v[0] = vrA[db * 2]; vf.v[1] = vrA[db * 2 + 1]; }
        acc[db] = __builtin_amdgcn_mfma_f32_32x32x16_bf16(vf.s, pa.s, acc[db], 0, 0, 0);
      }
    }
  }

  // ---- epilogue: O^T accum -> ctx[q][d], lane writes its own q-row ----
  float inv = 1.0f / l_run;
  unsigned short* Co = ctx + (baseRow + qrow) * 2048 + h * 128;
#pragma unroll
  for (int db = 0; db < 4; ++db)
#pragma unroll
    for (int g = 0; g < 4; ++g) {
      ushortv4 v;
#pragma unroll
      for (int j = 0; j < 4; ++j) v[j] = f2bf(acc[db][4 * g + j] * inv);
      *(ushortv4*)(Co + db * 32 + g * 8 + hi * 4) = v;
    }
#undef STAGE
}

extern "C" void kernel_launch(void* const* d_in, const int* in_sizes, int n_in,
                              void* d_out, int out_size, void* d_ws, size_t ws_size,
                              hipStream_t stream) {
  const int* positions = (const int*)d_in[0];
  const float* hidden = (const float*)d_in[1];
  const float* w_qkv = (const float*)d_in[2];
  const float* q_norm_w = (const float*)d_in[3];
  const float* k_norm_w = (const float*)d_in[4];
  const float* w_o = (const float*)d_in[5];
  float* out = (float*)d_out;

  char* ws = (char*)d_ws;
  unsigned short* hA    = (unsigned short*)(ws);              // 8192x2048 bf16, reused as ctx
  unsigned short* wqkvT = (unsigned short*)(ws + 33554432);   // 4096x2048 bf16
  unsigned short* woT   = (unsigned short*)(ws + 50331648);   // 2048x2048 bf16
  unsigned short* qkv   = (unsigned short*)(ws + 58720256);   // 8192x4096 bf16
  unsigned short* ctx   = hA;

  k_cvt<<<16384, 256, 0, stream>>>(hidden, hA, (8192 * 2048) / 4);
  k_transpose_cvt<<<dim3(64, 32), 256, 0, stream>>>(w_qkv, wqkvT, 2048, 4096);
  k_transpose_cvt<<<dim3(32, 32), 256, 0, stream>>>(w_o, woT, 2048, 2048);
  // qkv = hidden @ w_qkv : M=8192, N=4096, K=2048, bf16 out (256^2 tiles)
  k_gemm256<1><<<dim3(16, 32), 512, 0, stream>>>(hA, wqkvT, qkv, 8192, 4096, 2048);
  k_normrope<<<49152, 256, 0, stream>>>(qkv, positions, q_norm_w, k_norm_w);
  k_attn<<<dim3(8, 64), 512, 0, stream>>>(qkv, ctx);
  // out = ctx @ w_o : M=8192, N=2048, K=2048, f32 out (256^2 tiles)
  k_gemm256<0><<<dim3(8, 32), 512, 0, stream>>>(ctx, woT, out, 8192, 2048, 2048);
}

// Round 16
// 410.374 us; speedup vs baseline: 1.0196x; 1.0196x over previous
//
#include <hip/hip_runtime.h>

#define S_LEN 2048
#define QKV_N 4096
// SCALE_Q * log2(e): logits land in log2 domain, softmax uses v_exp_f32 (exp2)
#define SCALE_Q_LOG2E 0.12751744461f

typedef __attribute__((ext_vector_type(8))) short short8;
typedef __attribute__((ext_vector_type(4))) float f32x4;
typedef __attribute__((ext_vector_type(16))) float f32x16;
typedef __attribute__((ext_vector_type(4))) float floatv4;
typedef __attribute__((ext_vector_type(4))) unsigned short ushortv4;
typedef __attribute__((ext_vector_type(2))) unsigned int uint2v;

__device__ __forceinline__ float bf2f(unsigned short u) {
  union { unsigned u; float f; } x; x.u = ((unsigned)u) << 16; return x.f;
}
__device__ __forceinline__ unsigned short f2bf(float f) {
  union { float f; unsigned u; } x; x.f = f;
  unsigned r = x.u + 0x7fffu + ((x.u >> 16) & 1u);
  return (unsigned short)(r >> 16);
}

typedef const unsigned int __attribute__((address_space(1)))* gas1_t;
typedef unsigned int __attribute__((address_space(3)))* las3_t;
#define GLL16(g, l) __builtin_amdgcn_global_load_lds((gas1_t)(const void*)(g), (las3_t)(void*)(l), 16, 0, 0)

// fast exp2: raw v_exp_f32, no libm fixup path
#define EXP2F(x) __builtin_amdgcn_exp2f(x)

// ---------------- fused prep: cvt (hidden f32->bf16) + 2 transposes ----------------
// R16: one launch instead of three. blocks [0,16384): cvt; [16384,18432):
// w_qkv transpose (64x32 tiles); [18432,19456): w_o transpose (32x32).
__global__ __launch_bounds__(256) void k_prep(const float* __restrict__ hidden,
                                              unsigned short* __restrict__ hA,
                                              const float* __restrict__ w_qkv,
                                              unsigned short* __restrict__ wqkvT,
                                              const float* __restrict__ w_o,
                                              unsigned short* __restrict__ woT) {
  __shared__ float t[64][65];
  const int blk = blockIdx.x;
  if (blk < 16384) {
    int i = blk * 256 + threadIdx.x;
    floatv4 v = ((const floatv4*)hidden)[i];
    ushortv4 o;
    o[0] = f2bf(v[0]); o[1] = f2bf(v[1]); o[2] = f2bf(v[2]); o[3] = f2bf(v[3]);
    ((ushortv4*)hA)[i] = o;
    return;
  }
  const float* in;
  unsigned short* out;
  int bx, by, R, C;
  if (blk < 18432) {
    in = w_qkv; out = wqkvT; R = 2048; C = 4096;
    int bi = blk - 16384; bx = bi & 63; by = bi >> 6;
  } else {
    in = w_o; out = woT; R = 2048; C = 2048;
    int bi = blk - 18432; bx = bi & 31; by = bi >> 5;
  }
#pragma unroll
  for (int i = 0; i < 16; ++i) {
    int idx = threadIdx.x + i * 256;
    int r = idx >> 6, c = idx & 63;
    t[r][c] = in[(size_t)(by * 64 + r) * C + bx * 64 + c];
  }
  __syncthreads();
#pragma unroll
  for (int i = 0; i < 16; ++i) {
    int idx = threadIdx.x + i * 256;
    int r = idx >> 6, c = idx & 63;
    out[(size_t)(bx * 64 + r) * R + by * 64 + c] = f2bf(t[c][r]);
  }
}

// ---------------- 256x256x(BK=64) bf16 GEMM, 8 waves, 4-phase pipelined ----------------
// R12 known-best: 16x16x32 MFMA, phases = (k-slice, m-half), 24 conflict-free
// reads/tile, spread staging, vmcnt(0)+barrier at p==3 only.
template <int OUT_BF16>
__global__ __launch_bounds__(512, 2) void k_gemm256(const unsigned short* __restrict__ A,
                                                    const unsigned short* __restrict__ BT,
                                                    void* __restrict__ Cout,
                                                    int M, int N, int K) {
  const int tid = threadIdx.x;
  const int lane = tid & 63;
  const int wid = tid >> 6;
  const int wr = wid >> 2;          // 0..1 over M (128 rows each)
  const int wc = wid & 3;           // 0..3 over N (64 cols each)
  const int lr = lane & 15, lg = lane >> 4;

  // T1: bijective XCD-aware block swizzle (nwg % 8 == 0)
  const int gx = gridDim.x;
  const int nwg = gx * gridDim.y;
  const int lid = blockIdx.y * gx + blockIdx.x;
  const int qc = nwg >> 3;
  const int swz = (lid & 7) * qc + (lid >> 3);
  const int row0 = (swz / gx) * 256, col0 = (swz % gx) * 256;

  __shared__ __align__(16) unsigned short As[2][256 * 64];
  __shared__ __align__(16) unsigned short Bs[2][256 * 64];

  f32x4 acc[8][4];
#pragma unroll
  for (int m = 0; m < 8; ++m)
#pragma unroll
    for (int n = 0; n < 4; ++n) acc[m][n] = (f32x4){0.f, 0.f, 0.f, 0.f};

  const int r1 = tid >> 3, c1 = tid & 7;
  const int r2 = (tid + 512) >> 3, c2 = (tid + 512) & 7;
  const size_t so1 = (size_t)r1 * K + (size_t)((c1 ^ (r1 & 7)) * 8);
  const size_t so2 = (size_t)r2 * K + (size_t)((c2 ^ (r2 & 7)) * 8);
  const unsigned ld1 = (unsigned)tid * 16, ld2 = (unsigned)(tid + 512) * 16;

  const unsigned short* Abase = A + (size_t)row0 * K;
  const unsigned short* Bbase = BT + (size_t)col0 * K;

  auto stage = [&](int ph, int kt, int buf) {
    const size_t hb = (size_t)(ph >> 1) * 128 * K + (size_t)kt * 64;
    const unsigned short* src;
    unsigned short* dst;
    if (ph & 1) { src = Bbase + hb; dst = &Bs[buf][(ph >> 1) * 128 * 64]; }
    else        { src = Abase + hb; dst = &As[buf][(ph >> 1) * 128 * 64]; }
    GLL16(src + so1, (char*)dst + ld1);
    GLL16(src + so2, (char*)dst + ld2);
  };

#pragma unroll
  for (int ph = 0; ph < 4; ++ph) stage(ph, 0, 0);
  asm volatile("s_waitcnt vmcnt(0)" ::: "memory");
  __builtin_amdgcn_s_barrier();

  const int NT = K >> 6;
  for (int t = 0; t < NT; ++t) {
    const int cur = t & 1;
    const char* Ab = (const char*)&As[cur][0];
    const char* Bb = (const char*)&Bs[cur][0];
    short8 bf[4];
#pragma unroll
    for (int p = 0; p < 4; ++p) {
      const int ks = p >> 1, half = p & 1;
      short8 af[4];
#pragma unroll
      for (int m = 0; m < 4; ++m) {
        int rA = wr * 128 + (half * 4 + m) * 16 + lr;
        af[m] = *(const short8*)(Ab +
                ((rA * 128 + (ks * 4 + lg) * 16) ^ ((rA & 7) << 4)));
      }
      if (half == 0) {
#pragma unroll
        for (int n = 0; n < 4; ++n) {
          int rB = wc * 64 + n * 16 + lr;
          bf[n] = *(const short8*)(Bb +
                  ((rB * 128 + (ks * 4 + lg) * 16) ^ ((rB & 7) << 4)));
        }
      }
      if (t + 1 < NT) stage(p, t + 1, cur ^ 1);
      __builtin_amdgcn_sched_barrier(0);
      __builtin_amdgcn_s_setprio(1);
#pragma unroll
      for (int m = 0; m < 4; ++m)
#pragma unroll
        for (int n = 0; n < 4; ++n)
          acc[half * 4 + m][n] = __builtin_amdgcn_mfma_f32_16x16x32_bf16(
              af[m], bf[n], acc[half * 4 + m][n], 0, 0, 0);
      __builtin_amdgcn_s_setprio(0);
      if (p == 3) asm volatile("s_waitcnt vmcnt(0)" ::: "memory");
      __builtin_amdgcn_s_barrier();
    }
  }

  if (OUT_BF16) {
    unsigned short* C = (unsigned short*)Cout;
#pragma unroll
    for (int m = 0; m < 8; ++m)
#pragma unroll
      for (int n = 0; n < 4; ++n)
#pragma unroll
        for (int r = 0; r < 4; ++r)
          C[(size_t)(row0 + wr * 128 + m * 16 + 4 * lg + r) * N + col0 + wc * 64 + n * 16 + lr] =
              f2bf(acc[m][n][r]);
  } else {
    float* C = (float*)Cout;
#pragma unroll
    for (int m = 0; m < 8; ++m)
#pragma unroll
      for (int n = 0; n < 4; ++n)
#pragma unroll
        for (int r = 0; r < 4; ++r)
          C[(size_t)(row0 + wr * 128 + m * 16 + 4 * lg + r) * N + col0 + wc * 64 + n * 16 + lr] =
              acc[m][n][r];
  }
}

// ---------------- per-head RMSNorm + RoPE (in-place on bf16 qkv) ----------------
// R12-exact scalar version (R15's u32 vectorization doubled the trig count --
// lane->(l, l+64) mapping shares one rope freq per lane; reverted).
__global__ __launch_bounds__(256) void k_normrope(unsigned short* __restrict__ qkv,
                                                  const int* __restrict__ pos,
                                                  const float* __restrict__ qw,
                                                  const float* __restrict__ kw) {
  int lane = threadIdx.x & 63;
  int wv = (blockIdx.x << 2) + (threadIdx.x >> 6);
  int bs = wv / 24, hr = wv - bs * 24;
  bool isq = hr < 16;
  int col0 = isq ? hr * 128 : 2048 + (hr - 16) * 128;
  unsigned short* row = qkv + (size_t)bs * QKV_N + col0;
  float x1 = bf2f(row[lane]), x2 = bf2f(row[lane + 64]);
  float ss = x1 * x1 + x2 * x2;
#pragma unroll
  for (int m = 1; m < 64; m <<= 1) ss += __shfl_xor(ss, m, 64);
  float rn = rsqrtf(ss * (1.0f / 128.0f) + 1e-6f);
  const float* w = isq ? qw : kw;
  x1 *= rn * w[lane];
  x2 *= rn * w[lane + 64];
  float p = (float)pos[bs];
  float freq = exp2f(-(float)lane * 0.20762050593045951f);
  float ang = p * freq;
  float sn = __sinf(ang), cs = __cosf(ang);
  float o1 = x1 * cs - x2 * sn;
  float o2 = x2 * cs + x1 * sn;
  // Q absorbs SCALE * log2(e) so attn softmax runs in exp2 domain
  float sc = isq ? SCALE_Q_LOG2E : 1.0f;
  row[lane] = f2bf(o1 * sc);
  row[lane + 64] = f2bf(o2 * sc);
}

// ---------------- flash attention, 8-warp swapped-QK^T structure ----------------
// grid (S/256, B*NH); 8 waves x 32 q-rows. KVBLK=64, 32x32x16 MFMA.
// R10-best exact: XCD remap + PV tr-read pipeline, permlane repack,
// log2-domain softmax via raw v_exp_f32, serial max/sum chains.
__global__ __launch_bounds__(512, 2) void k_attn(const unsigned short* __restrict__ qkv,
                                                 unsigned short* __restrict__ ctx) {
  const int tid = threadIdx.x;
  const int lane = tid & 63;
  const int wid = tid >> 6;
  const int hi = lane >> 5;
  const int l15 = lane & 15;
  const int q31 = lane & 31;
  // XCD remap: give each XCD 8 consecutive bh (= 4 (b,kvh) K/V sets = 2MB, L2-fits)
  const int lid0 = blockIdx.y * 8 + blockIdx.x;
  const int xcd = lid0 & 7, idx = lid0 >> 3;
  const int bh = xcd * 8 + (idx & 7);
  const int qb = idx >> 3;
  const int b = bh >> 4, h = bh & 15, kvh = h >> 1;

  __shared__ __align__(16) unsigned short Ks[2][64 * 128];
  __shared__ __align__(16) unsigned short Vs[2][64 * 128];

  const size_t baseRow = (size_t)b * S_LEN;
  const int qrow = qb * 256 + wid * 32 + q31;

  const unsigned short* Qg = qkv + (baseRow + qrow) * QKV_N + h * 128;
  short8 qf[8];
#pragma unroll
  for (int c = 0; c < 8; ++c)
    qf[c] = *(const short8*)(Qg + c * 16 + hi * 8);

  const unsigned short* Kg = qkv + baseRow * QKV_N + 2048 + kvh * 128;
  const unsigned short* Vg = Kg + 1024;

  size_t ksrc[2], vsrc[2];
  unsigned sdst[2];
#pragma unroll
  for (int i = 0; i < 2; ++i) {
    int s = tid + i * 512;
    int krow = s >> 4, kc = s & 15;
    ksrc[i] = (size_t)krow * QKV_N + (size_t)((kc ^ (krow & 7)) * 8);
    int st = s >> 3, in8 = s & 7;
    int vkey = (st >> 3) * 4 + (in8 >> 1);
    int vj = ((st & 7) << 1) | (in8 & 1);
    vsrc[i] = (size_t)vkey * QKV_N + (size_t)(vj * 8);
    sdst[i] = (unsigned)s * 16;
  }

#define STAGE(T, BUF)                                                    \
  {                                                                      \
    size_t toff = (size_t)(T) * 64 * QKV_N;                              \
    GLL16(Kg + toff + ksrc[0], (char*)Ks[BUF] + sdst[0]);                \
    GLL16(Kg + toff + ksrc[1], (char*)Ks[BUF] + sdst[1]);                \
    GLL16(Vg + toff + vsrc[0], (char*)Vs[BUF] + sdst[0]);                \
    GLL16(Vg + toff + vsrc[1], (char*)Vs[BUF] + sdst[1]);                \
  }

  f32x16 acc[4];
#pragma unroll
  for (int d = 0; d < 4; ++d)
#pragma unroll
    for (int r = 0; r < 16; ++r) acc[d][r] = 0.f;
  float m_run = -1e30f, l_run = 0.f;

  const unsigned vbase = (unsigned)(uintptr_t)&Vs[0][0];
  const int sw = (q31 & 7) << 4;

  // issue 8 tr-reads for one ks-group into vr[8]
  auto tr_issue = [&](uint2v* vr, int ksg, unsigned vb) {
#pragma unroll
    for (int db = 0; db < 4; ++db)
#pragma unroll
      for (int rd = 0; rd < 2; ++rd) {
        int st = (ksg * 4 + hi * 2 + rd) * 8 + db * 2 + ((lane >> 4) & 1);
        unsigned a = vb + (unsigned)(st * 128 + l15 * 8);
        asm volatile("ds_read_b64_tr_b16 %0, %1" : "=v"(vr[db * 2 + rd]) : "v"(a));
      }
  };

  STAGE(0, 0);

  for (int t = 0; t < 32; ++t) {
    const int cur = t & 1;
    __builtin_amdgcn_s_barrier();          // all waves done reading buf[cur^1]
    __builtin_amdgcn_sched_barrier(0);
    if (t < 31) {
      STAGE(t + 1, cur ^ 1);
      asm volatile("s_waitcnt vmcnt(4)" ::: "memory");
    } else {
      asm volatile("s_waitcnt vmcnt(0)" ::: "memory");
    }
    __builtin_amdgcn_s_barrier();          // buf[cur] ready
    __builtin_amdgcn_sched_barrier(0);

    // ---- QK^T (swapped): p[key][q], lane owns q-row = lane&31 ----
    const char* Kb = (const char*)Ks[cur];
    f32x16 p0, p1;
#pragma unroll
    for (int r = 0; r < 16; ++r) { p0[r] = 0.f; p1[r] = 0.f; }
#pragma unroll
    for (int c = 0; c < 8; ++c) {
      int cb = c * 32 + hi * 16;
      short8 k0 = *(const short8*)(Kb + q31 * 256 + (cb ^ sw));
      short8 k1 = *(const short8*)(Kb + (32 + q31) * 256 + (cb ^ sw));
      p0 = __builtin_amdgcn_mfma_f32_32x32x16_bf16(k0, qf[c], p0, 0, 0, 0);
      p1 = __builtin_amdgcn_mfma_f32_32x32x16_bf16(k1, qf[c], p1, 0, 0, 0);
    }

    // ---- online softmax (log2 domain, raw v_exp_f32), in-lane ----
    float mt = p0[0];
#pragma unroll
    for (int r = 1; r < 16; ++r) mt = fmaxf(mt, p0[r]);
#pragma unroll
    for (int r = 0; r < 16; ++r) mt = fmaxf(mt, p1[r]);
    mt = fmaxf(mt, __shfl_xor(mt, 32, 64));
    if (!__all(mt - m_run <= 8.0f)) {     // defer-max: P bounded by 2^8
      float mnew = fmaxf(m_run, mt);
      float corr = EXP2F(m_run - mnew);
      l_run *= corr;
#pragma unroll
      for (int d = 0; d < 4; ++d)
#pragma unroll
        for (int r = 0; r < 16; ++r) acc[d][r] *= corr;
      m_run = mnew;
    }
    float s_loc = 0.f;
#pragma unroll
    for (int r = 0; r < 16; ++r) { p0[r] = EXP2F(p0[r] - m_run); s_loc += p0[r]; }
#pragma unroll
    for (int r = 0; r < 16; ++r) { p1[r] = EXP2F(p1[r] - m_run); s_loc += p1[r]; }
    l_run += s_loc + __shfl_xor(s_loc, 32, 64);

    // ---- PV (swapped): acc[d][q] += V^T x P; tr-reads pipelined 1 group ahead ----
    const unsigned vb = vbase + (unsigned)cur * 16384u;
    const float* pp0 = (const float*)&p0;
    const float* pp1 = (const float*)&p1;
    uint2v vrA[8], vrB[8];
    tr_issue(vrA, 0, vb);
#pragma unroll
    for (int ks = 0; ks < 4; ++ks) {
      const float* pr = ((ks & 2) ? pp1 : pp0) + (ks & 1) * 8;
      unsigned t0, t1, u0, u1;
      asm("v_cvt_pk_bf16_f32 %0, %1, %2" : "=v"(t0) : "v"(pr[0]), "v"(pr[1]));
      asm("v_cvt_pk_bf16_f32 %0, %1, %2" : "=v"(t1) : "v"(pr[2]), "v"(pr[3]));
      asm("v_cvt_pk_bf16_f32 %0, %1, %2" : "=v"(u0) : "v"(pr[4]), "v"(pr[5]));
      asm("v_cvt_pk_bf16_f32 %0, %1, %2" : "=v"(u1) : "v"(pr[6]), "v"(pr[7]));
      // cross-half repack in VALU (R3/R4/R9-validated): distinct source values,
      // no CSE-aliasing hazard (t0!=u0, t1!=u1 by construction)
      asm("v_permlane32_swap_b32 %0, %1" : "+v"(t0), "+v"(u0));
      asm("v_permlane32_swap_b32 %0, %1" : "+v"(t1), "+v"(u1));
      union { unsigned u[4]; short8 s; } pa;
      pa.u[0] = t0; pa.u[1] = t1; pa.u[2] = u0; pa.u[3] = u1;

      if (ks == 0) tr_issue(vrB, 1, vb);
      else if (ks == 1) tr_issue(vrA, 2, vb);
      else if (ks == 2) tr_issue(vrB, 3, vb);

      if (ks < 3) asm volatile("s_waitcnt lgkmcnt(8)" ::: "memory");
      else        asm volatile("s_waitcnt lgkmcnt(0)" ::: "memory");
      __builtin_amdgcn_sched_barrier(0);
#pragma unroll
      for (int db = 0; db < 4; ++db) {
        union { uint2v v[2]; short8 s; } vf;
        if (ks & 1) { vf.v[0] = vrB[db * 2]; vf.v[1] = vrB[db * 2 + 1]; }
        else        { vf.v[0] = vrA[db * 2]; vf.v[1] = vrA[db * 2 + 1]; }
        acc[db] = __builtin_amdgcn_mfma_f32_32x32x16_bf16(vf.s, pa.s, acc[db], 0, 0, 0);
      }
    }
  }

  // ---- epilogue: O^T accum -> ctx[q][d], lane writes its own q-row ----
  float inv = 1.0f / l_run;
  unsigned short* Co = ctx + (baseRow + qrow) * 2048 + h * 128;
#pragma unroll
  for (int db = 0; db < 4; ++db)
#pragma unroll
    for (int g = 0; g < 4; ++g) {
      ushortv4 v;
#pragma unroll
      for (int j = 0; j < 4; ++j) v[j] = f2bf(acc[db][4 * g + j] * inv);
      *(ushortv4*)(Co + db * 32 + g * 8 + hi * 4) = v;
    }
#undef STAGE
}

extern "C" void kernel_launch(void* const* d_in, const int* in_sizes, int n_in,
                              void* d_out, int out_size, void* d_ws, size_t ws_size,
                              hipStream_t stream) {
  const int* positions = (const int*)d_in[0];
  const float* hidden = (const float*)d_in[1];
  const float* w_qkv = (const float*)d_in[2];
  const float* q_norm_w = (const float*)d_in[3];
  const float* k_norm_w = (const float*)d_in[4];
  const float* w_o = (const float*)d_in[5];
  float* out = (float*)d_out;

  char* ws = (char*)d_ws;
  unsigned short* hA    = (unsigned short*)(ws);              // 8192x2048 bf16, reused as ctx
  unsigned short* wqkvT = (unsigned short*)(ws + 33554432);   // 4096x2048 bf16
  unsigned short* woT   = (unsigned short*)(ws + 50331648);   // 2048x2048 bf16
  unsigned short* qkv   = (unsigned short*)(ws + 58720256);   // 8192x4096 bf16
  unsigned short* ctx   = hA;

  // fused prep: cvt + both weight transposes in one launch
  k_prep<<<19456, 256, 0, stream>>>(hidden, hA, w_qkv, wqkvT, w_o, woT);
  // qkv = hidden @ w_qkv : M=8192, N=4096, K=2048, bf16 out (256^2 tiles)
  k_gemm256<1><<<dim3(16, 32), 512, 0, stream>>>(hA, wqkvT, qkv, 8192, 4096, 2048);
  k_normrope<<<49152, 256, 0, stream>>>(qkv, positions, q_norm_w, k_norm_w);
  k_attn<<<dim3(8, 64), 512, 0, stream>>>(qkv, ctx);
  // out = ctx @ w_o : M=8192, N=2048, K=2048, f32 out (256^2 tiles)
  k_gemm256<0><<<dim3(8, 32), 512, 0, stream>>>(ctx, woT, out, 8192, 2048, 2048);
}

// Round 17
// 379.424 us; speedup vs baseline: 1.1027x; 1.0816x over previous
//
#include <hip/hip_runtime.h>

#define S_LEN 2048
#define QKV_N 4096
// SCALE_Q * log2(e): logits land in log2 domain, softmax uses v_exp_f32 (exp2)
#define SCALE_Q_LOG2E 0.12751744461f

typedef __attribute__((ext_vector_type(8))) short short8;
typedef __attribute__((ext_vector_type(4))) float f32x4;
typedef __attribute__((ext_vector_type(16))) float f32x16;
typedef __attribute__((ext_vector_type(4))) float floatv4;
typedef __attribute__((ext_vector_type(4))) unsigned short ushortv4;
typedef __attribute__((ext_vector_type(2))) unsigned int uint2v;

__device__ __forceinline__ float bf2f(unsigned short u) {
  union { unsigned u; float f; } x; x.u = ((unsigned)u) << 16; return x.f;
}
__device__ __forceinline__ unsigned short f2bf(float f) {
  union { float f; unsigned u; } x; x.f = f;
  unsigned r = x.u + 0x7fffu + ((x.u >> 16) & 1u);
  return (unsigned short)(r >> 16);
}

typedef const unsigned int __attribute__((address_space(1)))* gas1_t;
typedef unsigned int __attribute__((address_space(3)))* las3_t;
#define GLL16(g, l) __builtin_amdgcn_global_load_lds((gas1_t)(const void*)(g), (las3_t)(void*)(l), 16, 0, 0)

// fast exp2: raw v_exp_f32, no libm fixup path
#define EXP2F(x) __builtin_amdgcn_exp2f(x)

// ---------------- fused prep: cvt (hidden f32->bf16) + 2 transposes ----------------
__global__ __launch_bounds__(256) void k_prep(const float* __restrict__ hidden,
                                              unsigned short* __restrict__ hA,
                                              const float* __restrict__ w_qkv,
                                              unsigned short* __restrict__ wqkvT,
                                              const float* __restrict__ w_o,
                                              unsigned short* __restrict__ woT) {
  __shared__ float t[64][65];
  const int blk = blockIdx.x;
  if (blk < 16384) {
    int i = blk * 256 + threadIdx.x;
    floatv4 v = ((const floatv4*)hidden)[i];
    ushortv4 o;
    o[0] = f2bf(v[0]); o[1] = f2bf(v[1]); o[2] = f2bf(v[2]); o[3] = f2bf(v[3]);
    ((ushortv4*)hA)[i] = o;
    return;
  }
  const float* in;
  unsigned short* out;
  int bx, by, R, C;
  if (blk < 18432) {
    in = w_qkv; out = wqkvT; R = 2048; C = 4096;
    int bi = blk - 16384; bx = bi & 63; by = bi >> 6;
  } else {
    in = w_o; out = woT; R = 2048; C = 2048;
    int bi = blk - 18432; bx = bi & 31; by = bi >> 5;
  }
#pragma unroll
  for (int i = 0; i < 16; ++i) {
    int idx = threadIdx.x + i * 256;
    int r = idx >> 6, c = idx & 63;
    t[r][c] = in[(size_t)(by * 64 + r) * C + bx * 64 + c];
  }
  __syncthreads();
#pragma unroll
  for (int i = 0; i < 16; ++i) {
    int idx = threadIdx.x + i * 256;
    int r = idx >> 6, c = idx & 63;
    out[(size_t)(bx * 64 + r) * R + by * 64 + c] = f2bf(t[c][r]);
  }
}

// ---------------- 256x256x(BK=64) bf16 GEMM, 8 waves, 4-phase pipelined ----------------
// R17: wave map 4M x 2N (wave = 64 rows x 128 cols = one full head) so the
// QKV variant (MODE 1) fuses RMSNorm+RoPE into the epilogue fully in-lane:
// RMS = n-sum(8) + shfl_xor over lr(16); RoPE pair (c,c+64) = (n,n+4).
// Main loop: same R12 schedule (spread staging, vmcnt(0)+barrier at p==3,
// 8/4 reads per phase alternating, 16 MFMA/phase, conflict-free swizzle).
// MODE 0: plain f32 C-write (O-proj).
template <int MODE>
__global__ __launch_bounds__(512, 2) void k_gemm256(const unsigned short* __restrict__ A,
                                                    const unsigned short* __restrict__ BT,
                                                    void* __restrict__ Cout,
                                                    int M, int N, int K,
                                                    const int* __restrict__ pos,
                                                    const float* __restrict__ qw,
                                                    const float* __restrict__ kw) {
  const int tid = threadIdx.x;
  const int lane = tid & 63;
  const int wid = tid >> 6;
  const int wr = wid >> 1;          // 0..3 over M (64 rows each)
  const int wc = wid & 1;           // 0..1 over N (128 cols each)
  const int lr = lane & 15, lg = lane >> 4;

  // T1: bijective XCD-aware block swizzle (nwg % 8 == 0)
  const int gx = gridDim.x;
  const int nwg = gx * gridDim.y;
  const int lid = blockIdx.y * gx + blockIdx.x;
  const int qc = nwg >> 3;
  const int swz = (lid & 7) * qc + (lid >> 3);
  const int row0 = (swz / gx) * 256, col0 = (swz % gx) * 256;

  __shared__ __align__(16) unsigned short As[2][256 * 64];
  __shared__ __align__(16) unsigned short Bs[2][256 * 64];

  f32x4 acc[4][8];
#pragma unroll
  for (int m = 0; m < 4; ++m)
#pragma unroll
    for (int n = 0; n < 8; ++n) acc[m][n] = (f32x4){0.f, 0.f, 0.f, 0.f};

  const int r1 = tid >> 3, c1 = tid & 7;
  const int r2 = (tid + 512) >> 3, c2 = (tid + 512) & 7;
  const size_t so1 = (size_t)r1 * K + (size_t)((c1 ^ (r1 & 7)) * 8);
  const size_t so2 = (size_t)r2 * K + (size_t)((c2 ^ (r2 & 7)) * 8);
  const unsigned ld1 = (unsigned)tid * 16, ld2 = (unsigned)(tid + 512) * 16;

  const unsigned short* Abase = A + (size_t)row0 * K;
  const unsigned short* Bbase = BT + (size_t)col0 * K;

  auto stage = [&](int ph, int kt, int buf) {
    const size_t hb = (size_t)(ph >> 1) * 128 * K + (size_t)kt * 64;
    const unsigned short* src;
    unsigned short* dst;
    if (ph & 1) { src = Bbase + hb; dst = &Bs[buf][(ph >> 1) * 128 * 64]; }
    else        { src = Abase + hb; dst = &As[buf][(ph >> 1) * 128 * 64]; }
    GLL16(src + so1, (char*)dst + ld1);
    GLL16(src + so2, (char*)dst + ld2);
  };

#pragma unroll
  for (int ph = 0; ph < 4; ++ph) stage(ph, 0, 0);
  asm volatile("s_waitcnt vmcnt(0)" ::: "memory");
  __builtin_amdgcn_s_barrier();

  const int NT = K >> 6;
  for (int t = 0; t < NT; ++t) {
    const int cur = t & 1;
    const char* Ab = (const char*)&As[cur][0];
    const char* Bb = (const char*)&Bs[cur][0];
    short8 af[4];
#pragma unroll
    for (int p = 0; p < 4; ++p) {
      const int ks = p >> 1, half = p & 1;
      short8 bf[4];
      if (half == 0) {
#pragma unroll
        for (int m = 0; m < 4; ++m) {
          int rA = wr * 64 + m * 16 + lr;
          af[m] = *(const short8*)(Ab +
                  ((rA * 128 + (ks * 4 + lg) * 16) ^ ((rA & 7) << 4)));
        }
      }
#pragma unroll
      for (int n = 0; n < 4; ++n) {
        int rB = wc * 128 + (half * 4 + n) * 16 + lr;
        bf[n] = *(const short8*)(Bb +
                ((rB * 128 + (ks * 4 + lg) * 16) ^ ((rB & 7) << 4)));
      }
      if (t + 1 < NT) stage(p, t + 1, cur ^ 1);
      __builtin_amdgcn_sched_barrier(0);
      __builtin_amdgcn_s_setprio(1);
#pragma unroll
      for (int m = 0; m < 4; ++m)
#pragma unroll
        for (int n = 0; n < 4; ++n)
          acc[m][half * 4 + n] = __builtin_amdgcn_mfma_f32_16x16x32_bf16(
              af[m], bf[n], acc[m][half * 4 + n], 0, 0, 0);
      __builtin_amdgcn_s_setprio(0);
      if (p == 3) asm volatile("s_waitcnt vmcnt(0)" ::: "memory");
      __builtin_amdgcn_s_barrier();
    }
  }

  if constexpr (MODE == 0) {
    float* C = (float*)Cout;
#pragma unroll
    for (int m = 0; m < 4; ++m)
#pragma unroll
      for (int n = 0; n < 8; ++n)
#pragma unroll
        for (int r = 0; r < 4; ++r)
          C[(size_t)(row0 + wr * 64 + m * 16 + 4 * lg + r) * N +
            col0 + wc * 128 + n * 16 + lr] = acc[m][n][r];
  } else {
    // MODE 1: qkv output with fused per-head RMSNorm + RoPE (v: plain).
    unsigned short* C = (unsigned short*)Cout;
    const int hcol0 = col0 + wc * 128;       // head-aligned (128-col) base
    if (col0 >= 3072) {                       // v region: plain bf16
#pragma unroll
      for (int m = 0; m < 4; ++m)
#pragma unroll
        for (int n = 0; n < 8; ++n)
#pragma unroll
          for (int r = 0; r < 4; ++r)
            C[(size_t)(row0 + wr * 64 + m * 16 + 4 * lg + r) * N +
              hcol0 + n * 16 + lr] = f2bf(acc[m][n][r]);
    } else {
      const bool isq = (col0 < 2048);
      const float scq = isq ? SCALE_Q_LOG2E : 1.0f;
      const float* w = isq ? qw : kw;
      float wv[8], fr[4];
#pragma unroll
      for (int n = 0; n < 8; ++n) wv[n] = w[n * 16 + lr];
#pragma unroll
      for (int j = 0; j < 4; ++j)
        fr[j] = exp2f(-(float)(j * 16 + lr) * 0.20762050593045951f);
#pragma unroll
      for (int m = 0; m < 4; ++m)
#pragma unroll
        for (int r = 0; r < 4; ++r) {
          const int row = row0 + wr * 64 + m * 16 + 4 * lg + r;
          // RMS over the head's 128 cols: in-lane n-sum + lr shfl tree
          float ss = 0.f;
#pragma unroll
          for (int n = 0; n < 8; ++n) ss += acc[m][n][r] * acc[m][n][r];
#pragma unroll
          for (int st = 1; st < 16; st <<= 1) ss += __shfl_xor(ss, st, 64);
          float rn = rsqrtf(ss * (1.0f / 128.0f) + 1e-6f);
          float p = (float)pos[row];
          unsigned short* Cr = C + (size_t)row * N + hcol0;
#pragma unroll
          for (int n = 0; n < 4; ++n) {
            float x1 = acc[m][n][r] * rn * wv[n];
            float x2 = acc[m][n + 4][r] * rn * wv[n + 4];
            float ang = p * fr[n];
            float cs = __cosf(ang), sn = __sinf(ang);
            Cr[n * 16 + lr]       = f2bf((x1 * cs - x2 * sn) * scq);
            Cr[(n + 4) * 16 + lr] = f2bf((x2 * cs + x1 * sn) * scq);
          }
        }
    }
  }
}

// ---------------- flash attention, 8-warp swapped-QK^T structure ----------------
// grid (S/256, B*NH); 8 waves x 32 q-rows. KVBLK=64, 32x32x16 MFMA.
// R10-best exact: XCD remap + PV tr-read pipeline, permlane repack,
// log2-domain softmax via raw v_exp_f32, serial max/sum chains.
__global__ __launch_bounds__(512, 2) void k_attn(const unsigned short* __restrict__ qkv,
                                                 unsigned short* __restrict__ ctx) {
  const int tid = threadIdx.x;
  const int lane = tid & 63;
  const int wid = tid >> 6;
  const int hi = lane >> 5;
  const int l15 = lane & 15;
  const int q31 = lane & 31;
  // XCD remap: give each XCD 8 consecutive bh (= 4 (b,kvh) K/V sets = 2MB, L2-fits)
  const int lid0 = blockIdx.y * 8 + blockIdx.x;
  const int xcd = lid0 & 7, idx = lid0 >> 3;
  const int bh = xcd * 8 + (idx & 7);
  const int qb = idx >> 3;
  const int b = bh >> 4, h = bh & 15, kvh = h >> 1;

  __shared__ __align__(16) unsigned short Ks[2][64 * 128];
  __shared__ __align__(16) unsigned short Vs[2][64 * 128];

  const size_t baseRow = (size_t)b * S_LEN;
  const int qrow = qb * 256 + wid * 32 + q31;

  const unsigned short* Qg = qkv + (baseRow + qrow) * QKV_N + h * 128;
  short8 qf[8];
#pragma unroll
  for (int c = 0; c < 8; ++c)
    qf[c] = *(const short8*)(Qg + c * 16 + hi * 8);

  const unsigned short* Kg = qkv + baseRow * QKV_N + 2048 + kvh * 128;
  const unsigned short* Vg = Kg + 1024;

  size_t ksrc[2], vsrc[2];
  unsigned sdst[2];
#pragma unroll
  for (int i = 0; i < 2; ++i) {
    int s = tid + i * 512;
    int krow = s >> 4, kc = s & 15;
    ksrc[i] = (size_t)krow * QKV_N + (size_t)((kc ^ (krow & 7)) * 8);
    int st = s >> 3, in8 = s & 7;
    int vkey = (st >> 3) * 4 + (in8 >> 1);
    int vj = ((st & 7) << 1) | (in8 & 1);
    vsrc[i] = (size_t)vkey * QKV_N + (size_t)(vj * 8);
    sdst[i] = (unsigned)s * 16;
  }

#define STAGE(T, BUF)                                                    \
  {                                                                      \
    size_t toff = (size_t)(T) * 64 * QKV_N;                              \
    GLL16(Kg + toff + ksrc[0], (char*)Ks[BUF] + sdst[0]);                \
    GLL16(Kg + toff + ksrc[1], (char*)Ks[BUF] + sdst[1]);                \
    GLL16(Vg + toff + vsrc[0], (char*)Vs[BUF] + sdst[0]);                \
    GLL16(Vg + toff + vsrc[1], (char*)Vs[BUF] + sdst[1]);                \
  }

  f32x16 acc[4];
#pragma unroll
  for (int d = 0; d < 4; ++d)
#pragma unroll
    for (int r = 0; r < 16; ++r) acc[d][r] = 0.f;
  float m_run = -1e30f, l_run = 0.f;

  const unsigned vbase = (unsigned)(uintptr_t)&Vs[0][0];
  const int sw = (q31 & 7) << 4;

  // issue 8 tr-reads for one ks-group into vr[8]
  auto tr_issue = [&](uint2v* vr, int ksg, unsigned vb) {
#pragma unroll
    for (int db = 0; db < 4; ++db)
#pragma unroll
      for (int rd = 0; rd < 2; ++rd) {
        int st = (ksg * 4 + hi * 2 + rd) * 8 + db * 2 + ((lane >> 4) & 1);
        unsigned a = vb + (unsigned)(st * 128 + l15 * 8);
        asm volatile("ds_read_b64_tr_b16 %0, %1" : "=v"(vr[db * 2 + rd]) : "v"(a));
      }
  };

  STAGE(0, 0);

  for (int t = 0; t < 32; ++t) {
    const int cur = t & 1;
    __builtin_amdgcn_s_barrier();          // all waves done reading buf[cur^1]
    __builtin_amdgcn_sched_barrier(0);
    if (t < 31) {
      STAGE(t + 1, cur ^ 1);
      asm volatile("s_waitcnt vmcnt(4)" ::: "memory");
    } else {
      asm volatile("s_waitcnt vmcnt(0)" ::: "memory");
    }
    __builtin_amdgcn_s_barrier();          // buf[cur] ready
    __builtin_amdgcn_sched_barrier(0);

    // ---- QK^T (swapped): p[key][q], lane owns q-row = lane&31 ----
    const char* Kb = (const char*)Ks[cur];
    f32x16 p0, p1;
#pragma unroll
    for (int r = 0; r < 16; ++r) { p0[r] = 0.f; p1[r] = 0.f; }
#pragma unroll
    for (int c = 0; c < 8; ++c) {
      int cb = c * 32 + hi * 16;
      short8 k0 = *(const short8*)(Kb + q31 * 256 + (cb ^ sw));
      short8 k1 = *(const short8*)(Kb + (32 + q31) * 256 + (cb ^ sw));
      p0 = __builtin_amdgcn_mfma_f32_32x32x16_bf16(k0, qf[c], p0, 0, 0, 0);
      p1 = __builtin_amdgcn_mfma_f32_32x32x16_bf16(k1, qf[c], p1, 0, 0, 0);
    }

    // ---- online softmax (log2 domain, raw v_exp_f32), in-lane ----
    float mt = p0[0];
#pragma unroll
    for (int r = 1; r < 16; ++r) mt = fmaxf(mt, p0[r]);
#pragma unroll
    for (int r = 0; r < 16; ++r) mt = fmaxf(mt, p1[r]);
    mt = fmaxf(mt, __shfl_xor(mt, 32, 64));
    if (!__all(mt - m_run <= 8.0f)) {     // defer-max: P bounded by 2^8
      float mnew = fmaxf(m_run, mt);
      float corr = EXP2F(m_run - mnew);
      l_run *= corr;
#pragma unroll
      for (int d = 0; d < 4; ++d)
#pragma unroll
        for (int r = 0; r < 16; ++r) acc[d][r] *= corr;
      m_run = mnew;
    }
    float s_loc = 0.f;
#pragma unroll
    for (int r = 0; r < 16; ++r) { p0[r] = EXP2F(p0[r] - m_run); s_loc += p0[r]; }
#pragma unroll
    for (int r = 0; r < 16; ++r) { p1[r] = EXP2F(p1[r] - m_run); s_loc += p1[r]; }
    l_run += s_loc + __shfl_xor(s_loc, 32, 64);

    // ---- PV (swapped): acc[d][q] += V^T x P; tr-reads pipelined 1 group ahead ----
    const unsigned vb = vbase + (unsigned)cur * 16384u;
    const float* pp0 = (const float*)&p0;
    const float* pp1 = (const float*)&p1;
    uint2v vrA[8], vrB[8];
    tr_issue(vrA, 0, vb);
#pragma unroll
    for (int ks = 0; ks < 4; ++ks) {
      const float* pr = ((ks & 2) ? pp1 : pp0) + (ks & 1) * 8;
      unsigned t0, t1, u0, u1;
      asm("v_cvt_pk_bf16_f32 %0, %1, %2" : "=v"(t0) : "v"(pr[0]), "v"(pr[1]));
      asm("v_cvt_pk_bf16_f32 %0, %1, %2" : "=v"(t1) : "v"(pr[2]), "v"(pr[3]));
      asm("v_cvt_pk_bf16_f32 %0, %1, %2" : "=v"(u0) : "v"(pr[4]), "v"(pr[5]));
      asm("v_cvt_pk_bf16_f32 %0, %1, %2" : "=v"(u1) : "v"(pr[6]), "v"(pr[7]));
      // cross-half repack in VALU (R3/R4/R9-validated): distinct source values,
      // no CSE-aliasing hazard (t0!=u0, t1!=u1 by construction)
      asm("v_permlane32_swap_b32 %0, %1" : "+v"(t0), "+v"(u0));
      asm("v_permlane32_swap_b32 %0, %1" : "+v"(t1), "+v"(u1));
      union { unsigned u[4]; short8 s; } pa;
      pa.u[0] = t0; pa.u[1] = t1; pa.u[2] = u0; pa.u[3] = u1;

      if (ks == 0) tr_issue(vrB, 1, vb);
      else if (ks == 1) tr_issue(vrA, 2, vb);
      else if (ks == 2) tr_issue(vrB, 3, vb);

      if (ks < 3) asm volatile("s_waitcnt lgkmcnt(8)" ::: "memory");
      else        asm volatile("s_waitcnt lgkmcnt(0)" ::: "memory");
      __builtin_amdgcn_sched_barrier(0);
#pragma unroll
      for (int db = 0; db < 4; ++db) {
        union { uint2v v[2]; short8 s; } vf;
        if (ks & 1) { vf.v[0] = vrB[db * 2]; vf.v[1] = vrB[db * 2 + 1]; }
        else        { vf.v[0] = vrA[db * 2]; vf.v[1] = vrA[db * 2 + 1]; }
        acc[db] = __builtin_amdgcn_mfma_f32_32x32x16_bf16(vf.s, pa.s, acc[db], 0, 0, 0);
      }
    }
  }

  // ---- epilogue: O^T accum -> ctx[q][d], lane writes its own q-row ----
  float inv = 1.0f / l_run;
  unsigned short* Co = ctx + (baseRow + qrow) * 2048 + h * 128;
#pragma unroll
  for (int db = 0; db < 4; ++db)
#pragma unroll
    for (int g = 0; g < 4; ++g) {
      ushortv4 v;
#pragma unroll
      for (int j = 0; j < 4; ++j) v[j] = f2bf(acc[db][4 * g + j] * inv);
      *(ushortv4*)(Co + db * 32 + g * 8 + hi * 4) = v;
    }
#undef STAGE
}

extern "C" void kernel_launch(void* const* d_in, const int* in_sizes, int n_in,
                              void* d_out, int out_size, void* d_ws, size_t ws_size,
                              hipStream_t stream) {
  const int* positions = (const int*)d_in[0];
  const float* hidden = (const float*)d_in[1];
  const float* w_qkv = (const float*)d_in[2];
  const float* q_norm_w = (const float*)d_in[3];
  const float* k_norm_w = (const float*)d_in[4];
  const float* w_o = (const float*)d_in[5];
  float* out = (float*)d_out;

  char* ws = (char*)d_ws;
  unsigned short* hA    = (unsigned short*)(ws);              // 8192x2048 bf16, reused as ctx
  unsigned short* wqkvT = (unsigned short*)(ws + 33554432);   // 4096x2048 bf16
  unsigned short* woT   = (unsigned short*)(ws + 50331648);   // 2048x2048 bf16
  unsigned short* qkv   = (unsigned short*)(ws + 58720256);   // 8192x4096 bf16
  unsigned short* ctx   = hA;

  // fused prep: cvt + both weight transposes in one launch
  k_prep<<<19456, 256, 0, stream>>>(hidden, hA, w_qkv, wqkvT, w_o, woT);
  // qkv = hidden @ w_qkv with fused RMSNorm+RoPE epilogue (M=8192,N=4096,K=2048)
  k_gemm256<1><<<dim3(16, 32), 512, 0, stream>>>(hA, wqkvT, qkv, 8192, 4096, 2048,
                                                 positions, q_norm_w, k_norm_w);
  k_attn<<<dim3(8, 64), 512, 0, stream>>>(qkv, ctx);
  // out = ctx @ w_o : M=8192, N=2048, K=2048, f32 out
  k_gemm256<0><<<dim3(8, 32), 512, 0, stream>>>(ctx, woT, out, 8192, 2048, 2048,
                                                nullptr, nullptr, nullptr);
}